// Round 1
// 615.095 us; speedup vs baseline: 1.0306x; 1.0306x over previous
//
#include <hip/hip_runtime.h>
#include <math.h>

#define Bq 32
#define Cq 256
#define Hq 96
#define Wq 96
#define HWq (Hq * Wq)      // 9216
#define KKq 9
#define CKq (Cq * KKq)     // 2304
#define NPLANES (Bq * Cq)  // 8192

typedef float f4 __attribute__((ext_vector_type(4)));

// ---------------- Kernel 1: global average pool per (b,c) plane ----------------
// Reads x forward (planes 0..8191) so the TAIL of x is what's left resident in
// the 256 MB L3 when conv starts (conv walks planes in reverse).
__global__ __launch_bounds__(256) void pool_kernel(const float* __restrict__ x,
                                                   float* __restrict__ pooled) {
    int plane = blockIdx.x;  // b*C + c
    const float4* px = (const float4*)(x + (size_t)plane * HWq);
    int t = threadIdx.x;
    float s = 0.f;
#pragma unroll
    for (int i = 0; i < 9; ++i) {       // 2304 float4 / 256 threads
        float4 v = px[t + i * 256];
        s += v.x + v.y + v.z + v.w;
    }
    // wave64 reduce
    for (int off = 32; off > 0; off >>= 1) s += __shfl_down(s, off, 64);
    __shared__ float wsum[4];
    if ((t & 63) == 0) wsum[t >> 6] = s;
    __syncthreads();
    if (t == 0) {
        pooled[plane] = (wsum[0] + wsum[1] + wsum[2] + wsum[3]) * (1.0f / HWq);
    }
}

// ---------------- Kernel 2: fused fc1+fc2 ----------------
// grid = (CKq/256 = 9, B = 32). Each block redundantly computes the full
// 256-wide h row for its batch (256 threads x dot-256 = trivial), keeps it in
// LDS, then produces its 256-entry slice of wdyn. Removes the fc1 launch,
// the 32-block latency-bound grid, and the global h round-trip.
__global__ __launch_bounds__(256) void fc_fused(const float* __restrict__ pooled,
                                                const float* __restrict__ w1,
                                                const float* __restrict__ b1,
                                                const float* __restrict__ w2,
                                                const float* __restrict__ b2,
                                                float* __restrict__ wdyn) {
    int b = blockIdx.y;
    int j = threadIdx.x;
    __shared__ float p[Cq];
    __shared__ float hs[Cq];
    p[j] = pooled[b * Cq + j];
    __syncthreads();
    // h[j] = gelu(dot(pooled[b,:], w1[j,:]) + b1[j])   (exact GELU)
    const float4* wrow = (const float4*)(w1 + (size_t)j * Cq);
    float acc = b1[j];
#pragma unroll 4
    for (int k = 0; k < Cq / 4; ++k) {
        float4 w = wrow[k];
        acc += p[4 * k] * w.x + p[4 * k + 1] * w.y + p[4 * k + 2] * w.z + p[4 * k + 3] * w.w;
    }
    hs[j] = 0.5f * acc * (1.0f + erff(acc * 0.70710678118654752440f));
    __syncthreads();
    // wdyn[b][m] = dot(h[b,:], w2[m,:]) + b2[m]
    int m = blockIdx.x * 256 + j;  // 0..2303
    const float4* w2row = (const float4*)(w2 + (size_t)m * Cq);
    float a2 = b2[m];
#pragma unroll 4
    for (int k = 0; k < Cq / 4; ++k) {
        float4 w = w2row[k];
        a2 += hs[4 * k] * w.x + hs[4 * k + 1] * w.y + hs[4 * k + 2] * w.z + hs[4 * k + 3] * w.w;
    }
    wdyn[b * CKq + m] = a2;
}

// ---------------- Kernel 3: reflect-pad 3x3 conv with per-plane dynamic weights ----------------
// One block per plane (9 groups/thread). Plane index REVERSED so conv's first
// reads hit the tail of x that pool_kernel left resident in L3.
// out stores are NONTEMPORAL so the 302 MB of writes don't evict x from L3 —
// this is what makes the second pass over x actually cache-resident.
__global__ __launch_bounds__(256) void conv_kernel(const float* __restrict__ x,
                                                   const float* __restrict__ wdyn,
                                                   float* __restrict__ out) {
    int plane = (NPLANES - 1) - blockIdx.x;
    const float* xp = x + (size_t)plane * HWq;
    float* op = out + (size_t)plane * HWq;
    const float* wd = wdyn + (size_t)plane * KKq;
    // broadcast load of the 9 weights (same address across lanes)
    float w0 = wd[0], w1 = wd[1], w2 = wd[2];
    float w3 = wd[3], w4 = wd[4], w5 = wd[5];
    float w6 = wd[6], w7 = wd[7], w8 = wd[8];
    int t = threadIdx.x;
#pragma unroll
    for (int it = 0; it < 9; ++it) {
        int g = t + it * 256;        // group of 4 outputs; 2304 groups per plane
        int hh = g / 24;             // output row
        int wq = (g % 24) * 4;       // output col of first element (aligned)
        int rm = (hh == 0) ? 1 : hh - 1;    // reflect: -1 -> 1
        int rp = (hh == 95) ? 94 : hh + 1;  // reflect: 96 -> 94
        const float* r0 = xp + rm * Wq;
        const float* r1 = xp + hh * Wq;
        const float* r2 = xp + rp * Wq;
        int li = (wq == 0) ? 1 : wq - 1;    // reflect left
        int ri = (wq == 92) ? 94 : wq + 4;  // reflect right (wq+4 == 96)
        float4 c0 = *(const float4*)(r0 + wq);
        float4 c1 = *(const float4*)(r1 + wq);
        float4 c2 = *(const float4*)(r2 + wq);
        float l0 = r0[li], l1 = r1[li], l2 = r2[li];
        float q0 = r0[ri], q1 = r1[ri], q2 = r2[ri];
        float4 o;
        // row above (taps w0,w1,w2)
        o.x = w0 * l0    + w1 * c0.x + w2 * c0.y;
        o.y = w0 * c0.x  + w1 * c0.y + w2 * c0.z;
        o.z = w0 * c0.y  + w1 * c0.z + w2 * c0.w;
        o.w = w0 * c0.z  + w1 * c0.w + w2 * q0;
        // same row (taps w3,w4,w5)
        o.x += w3 * l1   + w4 * c1.x + w5 * c1.y;
        o.y += w3 * c1.x + w4 * c1.y + w5 * c1.z;
        o.z += w3 * c1.y + w4 * c1.z + w5 * c1.w;
        o.w += w3 * c1.z + w4 * c1.w + w5 * q1;
        // row below (taps w6,w7,w8)
        o.x += w6 * l2   + w7 * c2.x + w8 * c2.y;
        o.y += w6 * c2.x + w7 * c2.y + w8 * c2.z;
        o.z += w6 * c2.y + w7 * c2.z + w8 * c2.w;
        o.w += w6 * c2.z + w7 * c2.w + w8 * q2;
        __builtin_nontemporal_store(*(f4*)&o, (f4*)(op + (size_t)g * 4));  // g*4 == hh*96 + wq
    }
}

extern "C" void kernel_launch(void* const* d_in, const int* in_sizes, int n_in,
                              void* d_out, int out_size, void* d_ws, size_t ws_size,
                              hipStream_t stream) {
    const float* x  = (const float*)d_in[0];
    const float* w1 = (const float*)d_in[1];
    const float* b1 = (const float*)d_in[2];
    const float* w2 = (const float*)d_in[3];
    const float* b2 = (const float*)d_in[4];
    float* out = (float*)d_out;

    float* pooled = (float*)d_ws;            // 8192 floats
    float* wdyn   = pooled + Bq * Cq;        // 73728 floats

    pool_kernel<<<NPLANES, 256, 0, stream>>>(x, pooled);
    fc_fused<<<dim3(CKq / 256, Bq), 256, 0, stream>>>(pooled, w1, b1, w2, b2, wdyn);
    conv_kernel<<<NPLANES, 256, 0, stream>>>(x, wdyn, out);
}

// Round 2
// 610.036 us; speedup vs baseline: 1.0391x; 1.0083x over previous
//
#include <hip/hip_runtime.h>
#include <math.h>

#define Bq 32
#define Cq 256
#define Hq 96
#define Wq 96
#define HWq (Hq * Wq)      // 9216
#define KKq 9
#define CKq (Cq * KKq)     // 2304
#define NPLANES (Bq * Cq)  // 8192
#define CHB 8              // batches per chunk: 8*256 planes * 36KB = 75 MB << 256 MB L3

typedef float f4 __attribute__((ext_vector_type(4)));

// ---------------- Kernel 1: global average pool per (b,c) plane ----------------
__global__ __launch_bounds__(256) void pool_kernel(const float* __restrict__ x,
                                                   float* __restrict__ pooled,
                                                   int plane0) {
    int plane = plane0 + blockIdx.x;  // b*C + c
    const float4* px = (const float4*)(x + (size_t)plane * HWq);
    int t = threadIdx.x;
    float s = 0.f;
#pragma unroll
    for (int i = 0; i < 9; ++i) {       // 2304 float4 / 256 threads
        float4 v = px[t + i * 256];
        s += v.x + v.y + v.z + v.w;
    }
    // wave64 reduce
    for (int off = 32; off > 0; off >>= 1) s += __shfl_down(s, off, 64);
    __shared__ float wsum[4];
    if ((t & 63) == 0) wsum[t >> 6] = s;
    __syncthreads();
    if (t == 0) {
        pooled[plane] = (wsum[0] + wsum[1] + wsum[2] + wsum[3]) * (1.0f / HWq);
    }
}

// ---------------- Kernel 2: fused fc1+fc2 (per batch-chunk) ----------------
// grid = (9, CHB). Each block redundantly computes the full 256-wide h row for
// its batch in LDS, then produces its 256-entry slice of wdyn.
__global__ __launch_bounds__(256) void fc_fused(const float* __restrict__ pooled,
                                                const float* __restrict__ w1,
                                                const float* __restrict__ b1,
                                                const float* __restrict__ w2,
                                                const float* __restrict__ b2,
                                                float* __restrict__ wdyn,
                                                int b0) {
    int b = b0 + blockIdx.y;
    int j = threadIdx.x;
    __shared__ float p[Cq];
    __shared__ float hs[Cq];
    p[j] = pooled[b * Cq + j];
    __syncthreads();
    // h[j] = gelu(dot(pooled[b,:], w1[j,:]) + b1[j])   (exact GELU)
    const float4* wrow = (const float4*)(w1 + (size_t)j * Cq);
    float acc = b1[j];
#pragma unroll 4
    for (int k = 0; k < Cq / 4; ++k) {
        float4 w = wrow[k];
        acc += p[4 * k] * w.x + p[4 * k + 1] * w.y + p[4 * k + 2] * w.z + p[4 * k + 3] * w.w;
    }
    hs[j] = 0.5f * acc * (1.0f + erff(acc * 0.70710678118654752440f));
    __syncthreads();
    // wdyn[b][m] = dot(h[b,:], w2[m,:]) + b2[m]
    int m = blockIdx.x * 256 + j;  // 0..2303
    const float4* w2row = (const float4*)(w2 + (size_t)m * Cq);
    float a2 = b2[m];
#pragma unroll 4
    for (int k = 0; k < Cq / 4; ++k) {
        float4 w = w2row[k];
        a2 += hs[4 * k] * w.x + hs[4 * k + 1] * w.y + hs[4 * k + 2] * w.z + hs[4 * k + 3] * w.w;
    }
    wdyn[b * CKq + m] = a2;
}

// ---------------- Kernel 3: reflect-pad 3x3 conv, LDS-staged plane ----------------
// One block per plane. The whole 36 KB plane is staged into LDS with one
// coalesced float4 pass; all 9-tap reads (including the strided edge scalars
// that previously thrashed L1) come from LDS. x reads hit L3 (chunked launch
// keeps the 75 MB chunk resident between pool and conv). out stores are
// nontemporal so the write stream doesn't evict the chunk from L2/L3.
__global__ __launch_bounds__(256) void conv_kernel(const float* __restrict__ x,
                                                   const float* __restrict__ wdyn,
                                                   float* __restrict__ out,
                                                   int plane0) {
    int plane = plane0 + blockIdx.x;
    const float* xp = x + (size_t)plane * HWq;
    float* op = out + (size_t)plane * HWq;
    const float* wd = wdyn + (size_t)plane * KKq;

    __shared__ float sx[HWq];          // 36864 B -> 4 blocks/CU
    int t = threadIdx.x;
    const float4* px = (const float4*)xp;
    float4* ps = (float4*)sx;
#pragma unroll
    for (int i = 0; i < 9; ++i) {      // coalesced stage: 2304 float4 / 256 thr
        ps[t + i * 256] = px[t + i * 256];
    }
    // broadcast load of the 9 weights (same address across lanes)
    float w0 = wd[0], w1 = wd[1], w2 = wd[2];
    float w3 = wd[3], w4 = wd[4], w5 = wd[5];
    float w6 = wd[6], w7 = wd[7], w8 = wd[8];
    __syncthreads();

#pragma unroll
    for (int it = 0; it < 9; ++it) {
        int g = t + it * 256;        // group of 4 outputs; 2304 groups per plane
        int hh = g / 24;             // output row
        int wq = (g % 24) * 4;       // output col of first element (aligned)
        int rm = (hh == 0) ? 1 : hh - 1;    // reflect: -1 -> 1
        int rp = (hh == 95) ? 94 : hh + 1;  // reflect: 96 -> 94
        const float* r0 = sx + rm * Wq;
        const float* r1 = sx + hh * Wq;
        const float* r2 = sx + rp * Wq;
        int li = (wq == 0) ? 1 : wq - 1;    // reflect left
        int ri = (wq == 92) ? 94 : wq + 4;  // reflect right (wq+4 == 96)
        float4 c0 = *(const float4*)(r0 + wq);
        float4 c1 = *(const float4*)(r1 + wq);
        float4 c2 = *(const float4*)(r2 + wq);
        float l0 = r0[li], l1 = r1[li], l2 = r2[li];
        float q0 = r0[ri], q1 = r1[ri], q2 = r2[ri];
        float4 o;
        // row above (taps w0,w1,w2)
        o.x = w0 * l0    + w1 * c0.x + w2 * c0.y;
        o.y = w0 * c0.x  + w1 * c0.y + w2 * c0.z;
        o.z = w0 * c0.y  + w1 * c0.z + w2 * c0.w;
        o.w = w0 * c0.z  + w1 * c0.w + w2 * q0;
        // same row (taps w3,w4,w5)
        o.x += w3 * l1   + w4 * c1.x + w5 * c1.y;
        o.y += w3 * c1.x + w4 * c1.y + w5 * c1.z;
        o.z += w3 * c1.y + w4 * c1.z + w5 * c1.w;
        o.w += w3 * c1.z + w4 * c1.w + w5 * q1;
        // row below (taps w6,w7,w8)
        o.x += w6 * l2   + w7 * c2.x + w8 * c2.y;
        o.y += w6 * c2.x + w7 * c2.y + w8 * c2.z;
        o.z += w6 * c2.y + w7 * c2.z + w8 * c2.w;
        o.w += w6 * c2.z + w7 * c2.w + w8 * q2;
        __builtin_nontemporal_store(*(f4*)&o, (f4*)(op + (size_t)g * 4));  // g*4 == hh*96 + wq
    }
}

extern "C" void kernel_launch(void* const* d_in, const int* in_sizes, int n_in,
                              void* d_out, int out_size, void* d_ws, size_t ws_size,
                              hipStream_t stream) {
    const float* x  = (const float*)d_in[0];
    const float* w1 = (const float*)d_in[1];
    const float* b1 = (const float*)d_in[2];
    const float* w2 = (const float*)d_in[3];
    const float* b2 = (const float*)d_in[4];
    float* out = (float*)d_out;

    float* pooled = (float*)d_ws;            // 8192 floats
    float* wdyn   = pooled + Bq * Cq;        // 73728 floats

    // Chunk by batch so each chunk's x (75 MB) stays L3-resident between its
    // pool pass and its conv pass -> x is fetched from HBM only once overall.
    for (int ck = 0; ck < Bq / CHB; ++ck) {
        int p0 = ck * CHB * Cq;
        pool_kernel<<<CHB * Cq, 256, 0, stream>>>(x, pooled, p0);
        fc_fused<<<dim3(CKq / 256, CHB), 256, 0, stream>>>(pooled, w1, b1, w2, b2, wdyn, ck * CHB);
        conv_kernel<<<CHB * Cq, 256, 0, stream>>>(x, wdyn, out, p0);
    }
}